// Round 5
// baseline (375.381 us; speedup 1.0000x reference)
//
#include <hip/hip_runtime.h>
#include <hip/hip_bf16.h>

// Problem constants (B=2, D=64, H=W=96)
constexpr int B_    = 2;
constexpr int N_    = 9216;      // 96*96
constexpr int ITERS = 4;

constexpr int MTQ     = 128;          // queries per workgroup (m-split: 32/wave)
constexpr int MBF     = N_ / MTQ;     // 72 m-blocks
constexpr int KS      = 4;            // key-split factor
constexpr int KEYS_WG = N_ / KS;      // 2304 keys per workgroup
constexpr int KT      = 64;           // keys per staged tile
constexpr int KTILES  = KEYS_WG / KT; // 36 tiles
constexpr int NWG     = B_ * MBF * KS;// 576 flash workgroups — all resident @3/CU
constexpr int PB      = 144;          // prep n-blocks of 64
constexpr int CGRID   = B_ * (N_ / 32); // 576 combine workgroups

constexpr float STEP = 0.5f;
constexpr float C2   = 0.43280851226668905f;  // KBW * log2(e)

using short8   = __attribute__((ext_vector_type(8))) short;
using float16v = __attribute__((ext_vector_type(16))) float;
typedef __attribute__((ext_vector_type(2))) __bf16 bf16x2;

__device__ __forceinline__ unsigned short f2bf(float f) {
  union { float f; unsigned u; } v; v.f = f;
  unsigned u = v.u;
  unsigned r = (u + 0x7fffu + ((u >> 16) & 1u)) >> 16;   // RNE
  return (unsigned short)r;
}

#if __has_builtin(__builtin_amdgcn_cvt_pk_bf16_f32)
__device__ __forceinline__ unsigned pk2bf(float a, float b) {
  bf16x2 r = __builtin_amdgcn_cvt_pk_bf16_f32(a, b);   // low <- a, high <- b, RNE
  union { bf16x2 h; unsigned u; } v; v.h = r; return v.u;
}
#else
__device__ __forceinline__ unsigned pk2bf(float a, float b) {
  return (unsigned)f2bf(a) | ((unsigned)f2bf(b) << 16);
}
#endif

// cs += lo(u) + hi(u) where u is a packed bf16 pair — 1 instr via dot2.
__device__ __forceinline__ float csum2(unsigned u, float cs) {
#if __has_builtin(__builtin_amdgcn_fdot2_f32_bf16)
  union { unsigned x; bf16x2 h; } a, o;
  a.x = u; o.x = 0x3f803f80u;                          // (1.0, 1.0) bf16
  return __builtin_amdgcn_fdot2_f32_bf16(a.h, o.h, cs, false);
#else
  union { unsigned u; float f; } lo, hi;
  lo.u = u << 16; hi.u = u & 0xffff0000u;
  return cs + lo.f + hi.f;
#endif
}

// Async global->LDS DMA, 16 B/lane; lds_base wave-uniform, lane i -> base+16i.
__device__ __forceinline__ void dma16(const unsigned short* g,
                                      unsigned short* lds_base, int lane) {
#if __has_builtin(__builtin_amdgcn_global_load_lds)
  __builtin_amdgcn_global_load_lds(
      (const __attribute__((address_space(1))) unsigned int*)g,
      (__attribute__((address_space(3))) unsigned int*)lds_base, 16, 0, 0);
#else
  *(int4*)((char*)lds_base + lane * 16) = *(const int4*)g;
#endif
}

// ---------------------------------------------------------------------------
// prep: x_in (fp32 [b][d][n]) -> out slice 0 (copy), Xbf bf16 [b][d][n],
//       XT bf16 [b][n][d] (LDS transpose)
// ---------------------------------------------------------------------------
__global__ void prep_kernel(const float* __restrict__ xin, float* __restrict__ out,
                            unsigned short* __restrict__ XT,
                            unsigned short* __restrict__ Xbf)
{
  const int bx = blockIdx.x;
  const int nb = bx % PB, b = bx / PB;
  const int n0 = nb * 64;
  const int tid = threadIdx.x;
  __shared__ float tile[64 * 65];

  #pragma unroll
  for (int r = 0; r < 16; ++r) {
    int idx = r * 256 + tid;
    int d = idx >> 6, j = idx & 63;
    float v = xin[((size_t)b * 64 + d) * N_ + n0 + j];
    out[(((size_t)b * 5 + 0) * 64 + d) * N_ + n0 + j] = v;
    Xbf[((size_t)b * 64 + d) * N_ + n0 + j] = f2bf(v);
    tile[d * 65 + j] = v;
  }
  __syncthreads();
  #pragma unroll
  for (int r = 0; r < 16; ++r) {
    int idx = r * 256 + tid;
    int nl = idx >> 6, d = idx & 63;
    XT[((size_t)b * N_ + n0 + nl) * 64 + d] = f2bf(tile[d * 65 + nl]);
  }
}

// ---------------------------------------------------------------------------
// flash (R11): R8 skeleton (MTQ=128 m-split, plain __syncthreads, dbuf->tbuf)
// + CROSS-INTERVAL QK/PV PIPELINE.
//
// R6-R10 post-mortem: per-wave cost is ~2.6k cy per 32x32 unit, invariant to
// sync/staging structure (counted vmcnt, depth-2 prefetch: no effect). Pipe
// content of a unit is only ~600 cy -> the wall is the intra-wave serial
// chain ds_read -> QK(4-dep MFMA) -> exp/pack/cs (serial VALU) -> PV, run in
// barrier lockstep by all waves (phase convoy on each pipe in turn).
// Fix: PV(tile t-1) depends on nothing in interval t. Carry W (16 packed
// regs) across the barrier; TRIPLE-buffer (48 KiB, cap still 3 blocks/CU per
// R10) so tile t-1's X-frags are still in LDS during interval t. Interval:
//   stage(t+1) -> setprio(1) PV(t-1) (8 reg-ready MFMAs) setprio(0)
//   -> QK(t) (af reads, 8 MFMAs, exp/pack -> W_cur) -> __syncthreads
// MFMA-issueable work exists at barrier exit; af-read latency and the exp
// VALU tail overlap PV; setprio now has role diversity (T5 precondition).
// cs split per-s (2 independent 8-deep dot chains).
// σ-trick (validated R6) unchanged; queries pre-scaled by C2 -> w = exp2(S).
// R9 lesson: stay 4 waves / bounds(256,3) (VGPR headroom 170).
// ---------------------------------------------------------------------------
__global__ void __launch_bounds__(256, 3) flash_kernel(
    const unsigned short* __restrict__ XT,
    const unsigned short* __restrict__ Xbf,
    float* __restrict__ pacc, float* __restrict__ pcs)
{
  const int bx   = blockIdx.x;
  const int ks   = bx & 3;
  const int mb   = (bx >> 2) % MBF;
  const int b    = bx / (MBF * KS);
  const int tid  = threadIdx.x;
  const int wave = tid >> 6, lane = tid & 63;
  const int c = lane & 31, h = lane >> 5;
  const int cp = (c & 0x13) | ((c & 4) << 1) | ((c & 8) >> 1);  // swap bits 2,3
  const int m0 = mb * MTQ;
  const int bpaddr = (lane ^ 32) << 2;      // ds_bpermute byte index (epilogue)

  const unsigned short* XTb = XT  + (size_t)b * N_ * 64;
  const unsigned short* Xb  = Xbf + (size_t)b * 64 * N_;

  __shared__ __align__(16) unsigned short sXT[3][KT * 64];  // [key][d]  8KiB x3
  __shared__ __align__(16) unsigned short sXB[3][64 * KT];  // [d][n]    8KiB x3

  // DMA lane coords: one dma16 covers 8 rows x 8 chunks; row&7 == rr, so the
  // write-side swizzle chunk gc = sc ^ rr is LANE-CONSTANT.
  const int rr = lane >> 3, sc = lane & 7;
  const int gc = sc ^ rr;

  const int n0g0 = ks * KEYS_WG;

  // per-lane global DMA pointers (tile 0); advance by constants per tile.
  const unsigned short* xtp  = XTb + (size_t)(n0g0 + wave * 16 + rr) * 64 + gc * 8;
  const unsigned short* xbp0 = Xb  + (size_t)(wave * 16 + rr) * N_ + n0g0 + gc * 8;
  const unsigned short* xbp1 = xbp0 + (size_t)8 * N_;

  auto stage = [&](int buf, const unsigned short* xt_,
                   const unsigned short* xb0_, const unsigned short* xb1_) {
    unsigned short* lt = &sXT[buf][wave * 16 * 64];   // 16 key rows / wave
    unsigned short* lb = &sXB[buf][wave * 16 * 64];   // 16 d rows / wave
    dma16(xt_,       lt,       lane);
    dma16(xt_ + 512, lt + 512, lane);
    dma16(xb0_,      lb,       lane);
    dma16(xb1_,      lb + 512, lane);
  };

  stage(0, xtp, xbp0, xbp1);                 // prologue DMA flies under qf setup
  xtp += KT * 64; xbp0 += KT; xbp1 += KT;

  // wave's resident query fragments (B-operand), pre-scaled by C2
  short8 qf[4];
  #pragma unroll
  for (int k = 0; k < 4; ++k) {
    short8 raw = *(const short8*)(XTb +
        (size_t)(m0 + wave * 32 + c) * 64 + k * 16 + h * 8);
    unsigned o[4];
    const unsigned* rw = (const unsigned*)&raw;
    #pragma unroll
    for (int p4 = 0; p4 < 4; ++p4) {
      union { unsigned u; float f; } lo, hi;
      lo.u = rw[p4] << 16; hi.u = rw[p4] & 0xffff0000u;
      o[p4] = pk2bf(lo.f * C2, hi.f * C2);
    }
    qf[k] = *(const short8*)o;
  }

  // persistent per-lane LDS read bases (buf 0); buf/s/dt -> offset immediates
  const int e = cp & 7;
  const unsigned short* afb[4];
  #pragma unroll
  for (int k = 0; k < 4; ++k)
    afb[k] = &sXT[0][cp * 64 + ((2 * k + h) ^ e) * 8];
  const int ec = c & 7;
  const unsigned short* bfb0[2], * bfb1[2];   // [s], k2=0 / k2=1
  #pragma unroll
  for (int s = 0; s < 2; ++s) {
    bfb0[s] = &sXB[0][c * 64 + ((4 * s +     h) ^ ec) * 8];
    bfb1[s] = &sXB[0][c * 64 + ((4 * s + 2 + h) ^ ec) * 8];
  }

  float16v zv;
  #pragma unroll
  for (int p = 0; p < 16; ++p) zv[p] = 0.f;
  float16v acc[2];
  acc[0] = zv; acc[1] = zv;
  float cs0 = 0.f, cs1 = 0.f;

  // pipelined W (packed bf16 weights) of the PREVIOUS tile: [s][8]
  unsigned qwp[2][8];
  #pragma unroll
  for (int s = 0; s < 2; ++s)
    #pragma unroll
    for (int g = 0; g < 8; ++g) qwp[s][g] = 0;

  __syncthreads();               // buf0 ready (drains prologue DMA + qf loads)

  #pragma unroll 3
  for (int t = 0; t < KTILES; ++t) {
    const int buf = t % 3;                   // constexpr after unroll-3
    if (t + 1 < KTILES) {                    // stage next tile (depth-1)
      stage((t + 1) % 3, xtp, xbp0, xbp1);
      xtp += KT * 64; xbp0 += KT; xbp1 += KT;
    }

    // ---- PV for tile t-1 (W in regs; X-frags still live in buf (t+2)%3) --
    if (t > 0) {
      const int pb = (t + 2) % 3;            // == (t-1) % 3, constexpr
      __builtin_amdgcn_s_setprio(1);
      #pragma unroll
      for (int s = 0; s < 2; ++s) {
        union { unsigned d[4]; short8 s8; } a20, a21;
        #pragma unroll
        for (int j = 0; j < 4; ++j) { a20.d[j] = qwp[s][j]; a21.d[j] = qwp[s][4 + j]; }
        short8 b20[2], b21[2];
        #pragma unroll
        for (int dt = 0; dt < 2; ++dt) {
          b20[dt] = *(const short8*)(bfb0[s] + pb * 4096 + dt * 2048);
          b21[dt] = *(const short8*)(bfb1[s] + pb * 4096 + dt * 2048);
        }
        #pragma unroll
        for (int dt = 0; dt < 2; ++dt)
          acc[dt] = __builtin_amdgcn_mfma_f32_32x32x16_bf16(a20.s8, b20[dt], acc[dt], 0, 0, 0);
        #pragma unroll
        for (int dt = 0; dt < 2; ++dt)
          acc[dt] = __builtin_amdgcn_mfma_f32_32x32x16_bf16(a21.s8, b21[dt], acc[dt], 0, 0, 0);
      }
      __builtin_amdgcn_s_setprio(0);
    }

    // ---- QK + exp for tile t -> W_cur ------------------------------------
    #pragma unroll
    for (int s = 0; s < 2; ++s) {
      short8 af[4];
      #pragma unroll
      for (int k = 0; k < 4; ++k)
        af[k] = *(const short8*)(afb[k] + buf * 4096 + s * 2048);

      float16v S = zv;
      #pragma unroll
      for (int k = 0; k < 4; ++k)
        S = __builtin_amdgcn_mfma_f32_32x32x16_bf16(af[k], qf[k], S, 0, 0, 0);

      // exp2 + packed bf16; colsum from the ROUNDED weights (dot2 with ones);
      // per-s cs chains (cs0 for s=0, cs1 for s=1) -> independent 8-deep.
      #pragma unroll
      for (int g = 0; g < 8; ++g) {
        float w0 = __builtin_amdgcn_exp2f(S[2 * g]);
        float w1 = __builtin_amdgcn_exp2f(S[2 * g + 1]);
        unsigned u = pk2bf(w0, w1);
        qwp[s][g] = u;                       // becomes W_prev next interval
        if (s) cs1 = csum2(u, cs1); else cs0 = csum2(u, cs0);
      }
    }

    __syncthreads();   // all waves done with bufs; stage(t+1) drained
  }

  // ---- final PV for tile KTILES-1 (buf (KTILES-1)%3 == 2) -----------------
  {
    constexpr int pb = (KTILES - 1) % 3;
    #pragma unroll
    for (int s = 0; s < 2; ++s) {
      union { unsigned d[4]; short8 s8; } a20, a21;
      #pragma unroll
      for (int j = 0; j < 4; ++j) { a20.d[j] = qwp[s][j]; a21.d[j] = qwp[s][4 + j]; }
      short8 b20[2], b21[2];
      #pragma unroll
      for (int dt = 0; dt < 2; ++dt) {
        b20[dt] = *(const short8*)(bfb0[s] + pb * 4096 + dt * 2048);
        b21[dt] = *(const short8*)(bfb1[s] + pb * 4096 + dt * 2048);
      }
      #pragma unroll
      for (int dt = 0; dt < 2; ++dt)
        acc[dt] = __builtin_amdgcn_mfma_f32_32x32x16_bf16(a20.s8, b20[dt], acc[dt], 0, 0, 0);
      #pragma unroll
      for (int dt = 0; dt < 2; ++dt)
        acc[dt] = __builtin_amdgcn_mfma_f32_32x32x16_bf16(a21.s8, b21[dt], acc[dt], 0, 0, 0);
    }
  }
  float cs = cs0 + cs1;

  // -------- epilogue: wave-disjoint outputs, direct global writes ----------
  union { float f; int i; } cu; cu.f = cs;
  cu.i = __builtin_amdgcn_ds_bpermute(bpaddr, cu.i);
  float cst = cs + cu.f;                     // both h-halves hold the total
  if (h == 0) pcs[(size_t)bx * 128 + wave * 32 + c] = cst;

  float* pw = pacc + (size_t)bx * (MTQ * 64);
  #pragma unroll
  for (int dt = 0; dt < 2; ++dt)
    #pragma unroll
    for (int p = 0; p < 16; ++p) {
      int m = wave * 32 + (p & 3) + 8 * (p >> 2) + 4 * h;
      pw[m * 64 + dt * 32 + c] = acc[dt][p];
    }
}

// ---------------------------------------------------------------------------
// combine: sum KS partials, normalize, blend with x_cur (= out slice t),
// write out slice t+1 + next iteration's Xbf / XT (bf16).
// 576 blocks, each owns a 32-query x 64-d slab of a 128-q flash block.
// ---------------------------------------------------------------------------
__global__ void combine_kernel(const float* __restrict__ pacc,
                               const float* __restrict__ pcs,
                               float* __restrict__ out,
                               unsigned short* __restrict__ XT,
                               unsigned short* __restrict__ Xbf, int t)
{
  const int bx  = blockIdx.x;
  const int q32 = bx % 288, b = bx / 288;
  const int m0  = q32 * 32;
  const int base = (b * MBF + (q32 >> 2)) * KS;  // flash block row (128 q)
  const int poff = (q32 & 3) * 2048;             // float offset into 128x64 blk
  const int coff = (q32 & 3) * 32;
  const int tid = threadIdx.x;
  __shared__ float accs[32 * 65];
  __shared__ float cstl[32];

  #pragma unroll
  for (int r = 0; r < 2; ++r) {
    int i4 = r * 256 + tid;                      // float4 idx within 32x64
    float4 s = make_float4(0.f, 0.f, 0.f, 0.f);
    #pragma unroll
    for (int k = 0; k < KS; ++k) {
      const float4* p = (const float4*)(pacc + (size_t)(base + k) * 8192 + poff);
      float4 v = p[i4];
      s.x += v.x; s.y += v.y; s.z += v.z; s.w += v.w;
    }
    int m = i4 >> 4, d0 = (i4 & 15) * 4;
    accs[m * 65 + d0 + 0] = s.x;
    accs[m * 65 + d0 + 1] = s.y;
    accs[m * 65 + d0 + 2] = s.z;
    accs[m * 65 + d0 + 3] = s.w;
  }
  if (tid < 32) {
    float cv = 0.f;
    #pragma unroll
    for (int k = 0; k < KS; ++k) cv += pcs[(size_t)(base + k) * 128 + coff + tid];
    cstl[tid] = cv;
  }
  __syncthreads();

  #pragma unroll
  for (int r = 0; r < 4; ++r) {
    int idx = r * 256 + tid;                    // 0..1023
    int ml = (idx & 15) * 2, d = idx >> 4;      // m fastest -> coalesced n
    float a0 = accs[ml * 65 + d], a1 = accs[(ml + 1) * 65 + d];
    size_t obase = (((size_t)b * 5 + t) * 64 + d) * N_ + m0 + ml;
    float2 xc = *(const float2*)(out + obase);
    float v0 = STEP * (a0 / cstl[ml])     + (1.f - STEP) * xc.x;
    float v1 = STEP * (a1 / cstl[ml + 1]) + (1.f - STEP) * xc.y;
    *(float2*)(out + obase + (size_t)64 * N_) = make_float2(v0, v1);  // slice t+1
    *(unsigned*)(Xbf + ((size_t)b * 64 + d) * N_ + m0 + ml) = pk2bf(v0, v1);
    accs[ml * 65 + d] = v0; accs[(ml + 1) * 65 + d] = v1;  // for transpose
  }
  __syncthreads();

  #pragma unroll
  for (int r = 0; r < 4; ++r) {
    int idx = r * 256 + tid;
    int m = idx >> 5, d = (idx & 31) * 2;       // d fastest -> coalesced XT row
    *(unsigned*)(XT + ((size_t)b * N_ + m0 + m) * 64 + d)
        = pk2bf(accs[m * 65 + d], accs[m * 65 + d + 1]);
  }
}

// ---------------------------------------------------------------------------
extern "C" void kernel_launch(void* const* d_in, const int* in_sizes, int n_in,
                              void* d_out, int out_size, void* d_ws, size_t ws_size,
                              hipStream_t stream)
{
  (void)in_sizes; (void)n_in; (void)out_size; (void)ws_size;
  const float* xin = (const float*)d_in[0];
  float* out = (float*)d_out;
  char* ws = (char*)d_ws;

  // workspace layout (23,887,872 B total — identical footprint to R1-R10):
  unsigned short* XT  = (unsigned short*)(ws);             //  2,359,296 B
  unsigned short* Xbf = (unsigned short*)(ws +  2359296);  //  2,359,296 B
  float*          pacc = (float*)(ws +  4718592);          // 18,874,368 B (576*8192*4)
  float*          pcs  = (float*)(ws + 23592960);          //    294,912 B (576*128*4)

  prep_kernel<<<B_ * PB, 256, 0, stream>>>(xin, out, XT, Xbf);
  for (int t = 0; t < ITERS; ++t) {
    flash_kernel<<<NWG, 256, 0, stream>>>(XT, Xbf, pacc, pcs);
    combine_kernel<<<CGRID, 256, 0, stream>>>(pacc, pcs, out, XT, Xbf, t);
  }
}

// Round 6
// 367.007 us; speedup vs baseline: 1.0228x; 1.0228x over previous
//
#include <hip/hip_runtime.h>
#include <hip/hip_bf16.h>

// Problem constants (B=2, D=64, H=W=96)
constexpr int B_    = 2;
constexpr int N_    = 9216;      // 96*96
constexpr int ITERS = 4;

constexpr int MTQ     = 128;          // queries per workgroup (m-split: 32/wave)
constexpr int MBF     = N_ / MTQ;     // 72 m-blocks
constexpr int KT      = 64;           // keys per staged tile
constexpr int PB      = 144;          // prep n-blocks of 64
constexpr int CGRID   = B_ * (N_ / 32); // 576 combine workgroups

constexpr float STEP = 0.5f;
constexpr float C2   = 0.43280851226668905f;  // KBW * log2(e)

using short8   = __attribute__((ext_vector_type(8))) short;
using float16v = __attribute__((ext_vector_type(16))) float;
typedef __attribute__((ext_vector_type(2))) __bf16 bf16x2;

__device__ __forceinline__ unsigned short f2bf(float f) {
  union { float f; unsigned u; } v; v.f = f;
  unsigned u = v.u;
  unsigned r = (u + 0x7fffu + ((u >> 16) & 1u)) >> 16;   // RNE
  return (unsigned short)r;
}

#if __has_builtin(__builtin_amdgcn_cvt_pk_bf16_f32)
__device__ __forceinline__ unsigned pk2bf(float a, float b) {
  bf16x2 r = __builtin_amdgcn_cvt_pk_bf16_f32(a, b);   // low <- a, high <- b, RNE
  union { bf16x2 h; unsigned u; } v; v.h = r; return v.u;
}
#else
__device__ __forceinline__ unsigned pk2bf(float a, float b) {
  return (unsigned)f2bf(a) | ((unsigned)f2bf(b) << 16);
}
#endif

// cs += lo(u) + hi(u) where u is a packed bf16 pair — 1 instr via dot2.
__device__ __forceinline__ float csum2(unsigned u, float cs) {
#if __has_builtin(__builtin_amdgcn_fdot2_f32_bf16)
  union { unsigned x; bf16x2 h; } a, o;
  a.x = u; o.x = 0x3f803f80u;                          // (1.0, 1.0) bf16
  return __builtin_amdgcn_fdot2_f32_bf16(a.h, o.h, cs, false);
#else
  union { unsigned u; float f; } lo, hi;
  lo.u = u << 16; hi.u = u & 0xffff0000u;
  return cs + lo.f + hi.f;
#endif
}

// Async global->LDS DMA, 16 B/lane; lds_base wave-uniform, lane i -> base+16i.
__device__ __forceinline__ void dma16(const unsigned short* g,
                                      unsigned short* lds_base, int lane) {
#if __has_builtin(__builtin_amdgcn_global_load_lds)
  __builtin_amdgcn_global_load_lds(
      (const __attribute__((address_space(1))) unsigned int*)g,
      (__attribute__((address_space(3))) unsigned int*)lds_base, 16, 0, 0);
#else
  *(int4*)((char*)lds_base + lane * 16) = *(const int4*)g;
#endif
}

// ---------------------------------------------------------------------------
// prep: x_in (fp32 [b][d][n]) -> out slice 0 (copy), Xbf bf16 [b][d][n],
//       XT bf16 [b][n][d] (LDS transpose)
// ---------------------------------------------------------------------------
__global__ void prep_kernel(const float* __restrict__ xin, float* __restrict__ out,
                            unsigned short* __restrict__ XT,
                            unsigned short* __restrict__ Xbf)
{
  const int bx = blockIdx.x;
  const int nb = bx % PB, b = bx / PB;
  const int n0 = nb * 64;
  const int tid = threadIdx.x;
  __shared__ float tile[64 * 65];

  #pragma unroll
  for (int r = 0; r < 16; ++r) {
    int idx = r * 256 + tid;
    int d = idx >> 6, j = idx & 63;
    float v = xin[((size_t)b * 64 + d) * N_ + n0 + j];
    out[(((size_t)b * 5 + 0) * 64 + d) * N_ + n0 + j] = v;
    Xbf[((size_t)b * 64 + d) * N_ + n0 + j] = f2bf(v);
    tile[d * 65 + j] = v;
  }
  __syncthreads();
  #pragma unroll
  for (int r = 0; r < 16; ++r) {
    int idx = r * 256 + tid;
    int nl = idx >> 6, d = idx & 63;
    XT[((size_t)b * N_ + n0 + nl) * 64 + d] = f2bf(tile[d * 65 + nl]);
  }
}

// ---------------------------------------------------------------------------
// flash (R12): OCCUPANCY experiment. R8-R11 post-mortems: MFMA pipe 22%,
// VALU 37%, LDS ~34% — three separate pipes, perfect overlap would give a
// ~1.9k-cy interval vs 5.0k measured; counted-vmcnt / setprio / W-carry all
// null => the binding constraint is 2.25 waves/SIMD (Occupancy 17%) unable
// to cover the serial chains. Total waves = B*(N/32)*KS, so KS=8 doubles
// occupancy to 4.5 waves/SIMD with 1152 blocks ALL resident (dbuf 32 KiB ->
// cap 5/CU; VGPR ~76 << 102 cap at bounds(256,5)).
// pacc = B*N*D*KS*4B = 37.7 MB at KS=8 -> workspace need 43.06 MB; the host
// BRANCHES on ws_size: KS=8 if it fits, else byte-identical R8 fallback
// (75.4 µs known). Kernel name (flash_kernel8/4) discloses the path taken.
// Body identical to R8 (best-measured skeleton): dbuf, stage-before-compute,
// single __syncthreads per tile, zero per-tile address VALU.
// σ-trick (validated R6) unchanged: af reads key row σ(c)=c with bits 2<->3
// swapped; MFMA C-layout delivers W already A-operand-ordered. Queries
// pre-scaled by C2 -> w = exp2(S).
// R9 lesson: never cap VGPR below ~100 (85-cap spill catastrophe).
// ---------------------------------------------------------------------------
template<int KSV>
__device__ __forceinline__ void flash_body(
    const unsigned short* __restrict__ XT,
    const unsigned short* __restrict__ Xbf,
    float* __restrict__ pacc, float* __restrict__ pcs)
{
  constexpr int KEYS = N_ / KSV;        // keys per workgroup
  constexpr int NT   = KEYS / KT;       // staged tiles
  const int bx   = blockIdx.x;
  const int ks   = bx % KSV;
  const int mb   = (bx / KSV) % MBF;
  const int b    = bx / (MBF * KSV);
  const int tid  = threadIdx.x;
  const int wave = tid >> 6, lane = tid & 63;
  const int c = lane & 31, h = lane >> 5;
  const int cp = (c & 0x13) | ((c & 4) << 1) | ((c & 8) >> 1);  // swap bits 2,3
  const int m0 = mb * MTQ;
  const int bpaddr = (lane ^ 32) << 2;      // ds_bpermute byte index (epilogue)

  const unsigned short* XTb = XT  + (size_t)b * N_ * 64;
  const unsigned short* Xb  = Xbf + (size_t)b * 64 * N_;

  __shared__ __align__(16) unsigned short sXT[2][KT * 64];  // [key][d]  8KiB x2
  __shared__ __align__(16) unsigned short sXB[2][64 * KT];  // [d][n]    8KiB x2

  // DMA lane coords: one dma16 covers 8 rows x 8 chunks; row&7 == rr, so the
  // write-side swizzle chunk gc = sc ^ rr is LANE-CONSTANT.
  const int rr = lane >> 3, sc = lane & 7;
  const int gc = sc ^ rr;

  const int n0g0 = ks * KEYS;

  // per-lane global DMA pointers (tile 0); advance by constants per tile.
  const unsigned short* xtp  = XTb + (size_t)(n0g0 + wave * 16 + rr) * 64 + gc * 8;
  const unsigned short* xbp0 = Xb  + (size_t)(wave * 16 + rr) * N_ + n0g0 + gc * 8;
  const unsigned short* xbp1 = xbp0 + (size_t)8 * N_;

  auto stage = [&](int buf, const unsigned short* xt_,
                   const unsigned short* xb0_, const unsigned short* xb1_) {
    unsigned short* lt = &sXT[buf][wave * 16 * 64];   // 16 key rows / wave
    unsigned short* lb = &sXB[buf][wave * 16 * 64];   // 16 d rows / wave
    dma16(xt_,       lt,       lane);
    dma16(xt_ + 512, lt + 512, lane);
    dma16(xb0_,      lb,       lane);
    dma16(xb1_,      lb + 512, lane);
  };

  stage(0, xtp, xbp0, xbp1);                 // prologue DMA flies under qf setup
  xtp += KT * 64; xbp0 += KT; xbp1 += KT;

  // wave's resident query fragments (B-operand), pre-scaled by C2
  short8 qf[4];
  #pragma unroll
  for (int k = 0; k < 4; ++k) {
    short8 raw = *(const short8*)(XTb +
        (size_t)(m0 + wave * 32 + c) * 64 + k * 16 + h * 8);
    unsigned o[4];
    const unsigned* rw = (const unsigned*)&raw;
    #pragma unroll
    for (int p4 = 0; p4 < 4; ++p4) {
      union { unsigned u; float f; } lo, hi;
      lo.u = rw[p4] << 16; hi.u = rw[p4] & 0xffff0000u;
      o[p4] = pk2bf(lo.f * C2, hi.f * C2);
    }
    qf[k] = *(const short8*)o;
  }

  // persistent per-lane LDS read bases (buf 0); buf/s/dt -> offset immediates
  const int e = cp & 7;
  const unsigned short* afb[4];
  #pragma unroll
  for (int k = 0; k < 4; ++k)
    afb[k] = &sXT[0][cp * 64 + ((2 * k + h) ^ e) * 8];
  const int ec = c & 7;
  const unsigned short* bfb0[2], * bfb1[2];   // [s], k2=0 / k2=1
  #pragma unroll
  for (int s = 0; s < 2; ++s) {
    bfb0[s] = &sXB[0][c * 64 + ((4 * s +     h) ^ ec) * 8];
    bfb1[s] = &sXB[0][c * 64 + ((4 * s + 2 + h) ^ ec) * 8];
  }

  float16v zv;
  #pragma unroll
  for (int p = 0; p < 16; ++p) zv[p] = 0.f;
  float16v acc[2];
  acc[0] = zv; acc[1] = zv;
  float cs = 0.f;

  __syncthreads();               // buf0 ready (drains prologue DMA + qf loads)

  #pragma unroll 2
  for (int t = 0; t < NT; ++t) {
    const int buf = t & 1;       // constexpr after unroll-2
    if (t + 1 < NT) {            // prefetch next tile FIRST (overlaps compute)
      stage(buf ^ 1, xtp, xbp0, xbp1);
      xtp += KT * 64; xbp0 += KT; xbp1 += KT;
    }

    #pragma unroll
    for (int s = 0; s < 2; ++s) {           // 2 key subtiles of 32
      // A-frags (keys, σ-permuted rows): sXT[buf][(s*32+cp)][chunk]
      short8 af[4];
      #pragma unroll
      for (int k = 0; k < 4; ++k)
        af[k] = *(const short8*)(afb[k] + buf * 4096 + s * 2048);

      float16v S = zv;
      #pragma unroll
      for (int k = 0; k < 4; ++k)
        S = __builtin_amdgcn_mfma_f32_32x32x16_bf16(af[k], qf[k], S, 0, 0, 0);

      // exp2 + packed bf16; colsum from the ROUNDED weights (dot2 with ones)
      unsigned q[8];
      #pragma unroll
      for (int g = 0; g < 8; ++g) {
        float w0 = __builtin_amdgcn_exp2f(S[2 * g]);
        float w1 = __builtin_amdgcn_exp2f(S[2 * g + 1]);
        unsigned u = pk2bf(w0, w1);
        q[g] = u;
        cs = csum2(u, cs);
      }

      // σ-permute: q[] is already A-operand ordered — no cross-lane moves
      union { unsigned d[4]; short8 s8; } a20, a21;
      a20.d[0] = q[0]; a20.d[1] = q[1]; a20.d[2] = q[2]; a20.d[3] = q[3];
      a21.d[0] = q[4]; a21.d[1] = q[5]; a21.d[2] = q[6]; a21.d[3] = q[7];

      // B-frags (X): sXB[buf][(dt*32+c)][chunk]
      short8 b20[2], b21[2];
      #pragma unroll
      for (int dt = 0; dt < 2; ++dt) {
        b20[dt] = *(const short8*)(bfb0[s] + buf * 4096 + dt * 2048);
        b21[dt] = *(const short8*)(bfb1[s] + buf * 4096 + dt * 2048);
      }
      #pragma unroll
      for (int dt = 0; dt < 2; ++dt)
        acc[dt] = __builtin_amdgcn_mfma_f32_32x32x16_bf16(a20.s8, b20[dt], acc[dt], 0, 0, 0);
      #pragma unroll
      for (int dt = 0; dt < 2; ++dt)
        acc[dt] = __builtin_amdgcn_mfma_f32_32x32x16_bf16(a21.s8, b21[dt], acc[dt], 0, 0, 0);
    }

    __syncthreads();   // all waves done with buf; prefetch DMA drained
  }

  // -------- epilogue: wave-disjoint outputs, direct global writes ----------
  union { float f; int i; } cu; cu.f = cs;
  cu.i = __builtin_amdgcn_ds_bpermute(bpaddr, cu.i);
  float cst = cs + cu.f;                     // both h-halves hold the total
  if (h == 0) pcs[(size_t)bx * 128 + wave * 32 + c] = cst;

  float* pw = pacc + (size_t)bx * (MTQ * 64);
  #pragma unroll
  for (int dt = 0; dt < 2; ++dt)
    #pragma unroll
    for (int p = 0; p < 16; ++p) {
      int m = wave * 32 + (p & 3) + 8 * (p >> 2) + 4 * h;
      pw[m * 64 + dt * 32 + c] = acc[dt][p];
    }
}

// KS=8 experiment: 1152 blocks, 4.5/CU resident (cap 5 via 32KiB LDS; VGPR
// cap 102 at min-5-waves/EU — body uses ~76).
__global__ void __launch_bounds__(256, 5) flash_kernel8(
    const unsigned short* __restrict__ XT, const unsigned short* __restrict__ Xbf,
    float* __restrict__ pacc, float* __restrict__ pcs)
{ flash_body<8>(XT, Xbf, pacc, pcs); }

// KS=4 fallback: exact R8 configuration (75.4 µs measured).
__global__ void __launch_bounds__(256, 3) flash_kernel4(
    const unsigned short* __restrict__ XT, const unsigned short* __restrict__ Xbf,
    float* __restrict__ pacc, float* __restrict__ pcs)
{ flash_body<4>(XT, Xbf, pacc, pcs); }

// ---------------------------------------------------------------------------
// combine: sum KSV partials, normalize, blend with x_cur (= out slice t),
// write out slice t+1 + next iteration's Xbf / XT (bf16).
// 576 blocks, each owns a 32-query x 64-d slab of a 128-q flash block.
// ---------------------------------------------------------------------------
template<int KSV>
__global__ void combine_kernel(const float* __restrict__ pacc,
                               const float* __restrict__ pcs,
                               float* __restrict__ out,
                               unsigned short* __restrict__ XT,
                               unsigned short* __restrict__ Xbf, int t)
{
  const int bx  = blockIdx.x;
  const int q32 = bx % 288, b = bx / 288;
  const int m0  = q32 * 32;
  const int base = (b * MBF + (q32 >> 2)) * KSV;  // flash block row (128 q)
  const int poff = (q32 & 3) * 2048;              // float offset into 128x64 blk
  const int coff = (q32 & 3) * 32;
  const int tid = threadIdx.x;
  __shared__ float accs[32 * 65];
  __shared__ float cstl[32];

  #pragma unroll
  for (int r = 0; r < 2; ++r) {
    int i4 = r * 256 + tid;                      // float4 idx within 32x64
    float4 s = make_float4(0.f, 0.f, 0.f, 0.f);
    #pragma unroll
    for (int k = 0; k < KSV; ++k) {
      const float4* p = (const float4*)(pacc + (size_t)(base + k) * 8192 + poff);
      float4 v = p[i4];
      s.x += v.x; s.y += v.y; s.z += v.z; s.w += v.w;
    }
    int m = i4 >> 4, d0 = (i4 & 15) * 4;
    accs[m * 65 + d0 + 0] = s.x;
    accs[m * 65 + d0 + 1] = s.y;
    accs[m * 65 + d0 + 2] = s.z;
    accs[m * 65 + d0 + 3] = s.w;
  }
  if (tid < 32) {
    float cv = 0.f;
    #pragma unroll
    for (int k = 0; k < KSV; ++k) cv += pcs[(size_t)(base + k) * 128 + coff + tid];
    cstl[tid] = cv;
  }
  __syncthreads();

  #pragma unroll
  for (int r = 0; r < 4; ++r) {
    int idx = r * 256 + tid;                    // 0..1023
    int ml = (idx & 15) * 2, d = idx >> 4;      // m fastest -> coalesced n
    float a0 = accs[ml * 65 + d], a1 = accs[(ml + 1) * 65 + d];
    size_t obase = (((size_t)b * 5 + t) * 64 + d) * N_ + m0 + ml;
    float2 xc = *(const float2*)(out + obase);
    float v0 = STEP * (a0 / cstl[ml])     + (1.f - STEP) * xc.x;
    float v1 = STEP * (a1 / cstl[ml + 1]) + (1.f - STEP) * xc.y;
    *(float2*)(out + obase + (size_t)64 * N_) = make_float2(v0, v1);  // slice t+1
    *(unsigned*)(Xbf + ((size_t)b * 64 + d) * N_ + m0 + ml) = pk2bf(v0, v1);
    accs[ml * 65 + d] = v0; accs[(ml + 1) * 65 + d] = v1;  // for transpose
  }
  __syncthreads();

  #pragma unroll
  for (int r = 0; r < 4; ++r) {
    int idx = r * 256 + tid;
    int m = idx >> 5, d = (idx & 31) * 2;       // d fastest -> coalesced XT row
    *(unsigned*)(XT + ((size_t)b * N_ + m0 + m) * 64 + d)
        = pk2bf(accs[m * 65 + d], accs[m * 65 + d + 1]);
  }
}

// ---------------------------------------------------------------------------
extern "C" void kernel_launch(void* const* d_in, const int* in_sizes, int n_in,
                              void* d_out, int out_size, void* d_ws, size_t ws_size,
                              hipStream_t stream)
{
  (void)in_sizes; (void)n_in; (void)out_size;
  const float* xin = (const float*)d_in[0];
  float* out = (float*)d_out;
  char* ws = (char*)d_ws;

  unsigned short* XT  = (unsigned short*)(ws);             //  2,359,296 B
  unsigned short* Xbf = (unsigned short*)(ws +  2359296);  //  2,359,296 B

  // KS=8 needs 4,718,592 + 1152*8192*4 + 1152*128*4 = 43,057,152 B.
  const size_t NEED8 = 4718592u + (size_t)1152 * 8192 * 4 + (size_t)1152 * 128 * 4;

  prep_kernel<<<B_ * PB, 256, 0, stream>>>(xin, out, XT, Xbf);

  if (ws_size >= NEED8) {
    float* pacc = (float*)(ws + 4718592);                        // 37,748,736 B
    float* pcs  = (float*)(ws + 4718592 + (size_t)1152 * 8192 * 4); // 589,824 B
    for (int t = 0; t < ITERS; ++t) {
      flash_kernel8<<<B_ * MBF * 8, 256, 0, stream>>>(XT, Xbf, pacc, pcs);
      combine_kernel<8><<<CGRID, 256, 0, stream>>>(pacc, pcs, out, XT, Xbf, t);
    }
  } else {
    float* pacc = (float*)(ws + 4718592);                        // 18,874,368 B
    float* pcs  = (float*)(ws + 23592960);                       //    294,912 B
    for (int t = 0; t < ITERS; ++t) {
      flash_kernel4<<<B_ * MBF * 4, 256, 0, stream>>>(XT, Xbf, pacc, pcs);
      combine_kernel<4><<<CGRID, 256, 0, stream>>>(pacc, pcs, out, XT, Xbf, t);
    }
  }
}